// Round 6
// baseline (99.138 us; speedup 1.0000x reference)
//
#include <hip/hip_runtime.h>

// Only the l=1 path reaches the output (g0/g2/c0/c2/w_tp0/w_tp2/L0/L2e are dead).
// t[i] = MLP(node i) @ (W_m2@w_tp1) + b_m2@w_tp1 ; enc = agg(segsum(t x sqrt3*pos)) @ (L1o@L_out)/64
// Node MLP on MFMA bf16, weights split hi+lo bf16 (error ~ f32). One wave = one block,
// L2..L5 weight fragments PERSISTENT in VGPRs across a grid-stride tile loop; L1/table/bias
// streamed (VMEM_READ may cross fences). In-place LDS act buffer; sched_barrier(0x7F)
// fences order DS only.

typedef __attribute__((ext_vector_type(8))) short bf16x8;
typedef __attribute__((ext_vector_type(4))) float f32x4;
typedef unsigned short ushort_t;

#define SBW 72   // LDS act-row stride in ushorts: 64 cols + 8 pad (144B rows: 16B-aligned, 2-way max bank alias)

__device__ __forceinline__ unsigned rnebits(float x) {   // RNE-rounded, bf16 in top 16 bits
    unsigned u = __float_as_uint(x);
    return u + 0x7fffu + ((u >> 16) & 1u);
}
__device__ __forceinline__ ushort_t f2bf(float x) { return (ushort_t)(rnebits(x) >> 16); }
__device__ __forceinline__ float bf2f(ushort_t h) { return __uint_as_float(((unsigned)h) << 16); }
#if __has_builtin(__builtin_amdgcn_perm)
__device__ __forceinline__ unsigned pack2bf(float lo, float hi) {   // lo -> low halfword
    return __builtin_amdgcn_perm(rnebits(hi), rnebits(lo), 0x07060302u);
}
#else
__device__ __forceinline__ unsigned pack2bf(float lo, float hi) {
    return (rnebits(hi) & 0xffff0000u) | (rnebits(lo) >> 16);
}
#endif
__device__ __forceinline__ void ds_order_fence() {   // DS ops may not cross; VMEM/VALU/MFMA may
    __builtin_amdgcn_sched_barrier(0x7F);
}

// gelu(x) = x - x * rcp(exp2(x*(C + Ca*x^2)) + 1);  C = 2*0.79788456*log2(e)
__device__ __forceinline__ float gelu(float x) {
    float x2 = x * x;
    float y  = x * fmaf(0.10294324f, x2, 2.3022082f);
    float e  = __builtin_amdgcn_exp2f(y);
    float r  = __builtin_amdgcn_rcpf(e + 1.0f);
    return fmaf(-x, r, x);
}

// ---------------- prep: fold weights (hi/lo bf16, transposed) + table bf16 + seg ----------------
// wb layout ([feat][K] row-major, ushort offsets):
//  W_rbf0 hi 0 / lo 2048 | W_rbf1 hi 4096 / lo 8192 | W_m0 hi 12288 / lo 18432
//  W_m1 hi 24576 / lo 28672 | Wc hi 32768 / lo 36864 | table_bf16 40960 (100x32) | end 44160
__global__ __launch_bounds__(256)
void prep_kernel(const float* __restrict__ W_rbf0, const float* __restrict__ W_rbf1,
                 const float* __restrict__ W_m0, const float* __restrict__ W_m1,
                 const float* __restrict__ W_m2, const float* __restrict__ b_m2,
                 const float* __restrict__ w_tp1,
                 const float* __restrict__ L1o, const float* __restrict__ L_out,
                 const float* __restrict__ node_table, const int* __restrict__ batch,
                 ushort_t* __restrict__ wb, float* __restrict__ bc,
                 float* __restrict__ Lcomb, int* __restrict__ seg, int N, int G)
{
    if (blockIdx.x >= 115) {   // ---- seg part ----
        int i = (blockIdx.x - 115) * 256 + threadIdx.x;
        if (i >= N) return;
        int bi = batch[i];
        int bprev = (i == 0) ? -1 : batch[i - 1];
        for (int g = bprev + 1; g <= bi; ++g) seg[g] = i;
        if (i == N - 1) for (int g = bi + 1; g <= G; ++g) seg[g] = N;
        return;
    }
    int idx = blockIdx.x * 256 + threadIdx.x;   // fold part, 29184 items
    float w;
    ushort_t *dh, *dl;
    if (idx < 2048) {                    // W_rbf0 [f][32]
        int f = idx >> 5, k = idx & 31;
        w = W_rbf0[k * 64 + f]; dh = wb + idx; dl = wb + 2048 + idx;
    } else if (idx < 6144) {             // W_rbf1 [f][64]
        int j = idx - 2048, f = j >> 6, k = j & 63;
        w = W_rbf1[k * 64 + f]; dh = wb + 4096 + j; dl = wb + 8192 + j;
    } else if (idx < 12288) {            // W_m0 [f][96]
        int j = idx - 6144, f = j / 96, k = j - 96 * f;
        w = W_m0[k * 64 + f]; dh = wb + 12288 + j; dl = wb + 18432 + j;
    } else if (idx < 16384) {            // W_m1 [f][64]
        int j = idx - 12288, f = j >> 6, k = j & 63;
        w = W_m1[k * 64 + f]; dh = wb + 24576 + j; dl = wb + 28672 + j;
    } else if (idx < 20480) {            // Wc[f=t_out][k=h_in] = sum_j W_m2[k][j]*w_tp1[j][f]
        int j = idx - 16384, f = j >> 6, k = j & 63;
        float s = 0.f;
        for (int jj = 0; jj < 64; ++jj) s = fmaf(W_m2[k * 64 + jj], w_tp1[jj * 64 + f], s);
        w = s; dh = wb + 32768 + j; dl = wb + 36864 + j;
    } else if (idx < 20544) {            // bc
        int b = idx - 20480;
        float s = 0.f;
        for (int k = 0; k < 64; ++k) s = fmaf(b_m2[k], w_tp1[k * 64 + b], s);
        bc[b] = s;
        return;
    } else if (idx < 25984) {            // Lcomb = (L1o@L_out)/64
        int j = idx - 20544, u = j / 85, v = j - 85 * u;
        float s = 0.f;
        for (int k = 0; k < 64; ++k) s = fmaf(L1o[u * 64 + k], L_out[k * 85 + v], s);
        Lcomb[j] = 0.015625f * s;
        return;
    } else if (idx < 29184) {            // node_table -> bf16 [100][32]
        int j = idx - 25984;
        wb[40960 + j] = f2bf(node_table[j]);
        return;
    } else return;
    ushort_t h = f2bf(w);
    *dh = h;
    *dl = f2bf(w - bf2f(h));
}

// ---------------- node MLP pieces ----------------
template<int ACT>
__device__ __forceinline__ void epilogueR(f32x4 (&acc)[4][4], ushort_t* buf, int lrow, int lcol) {
    #pragma unroll
    for (int m = 0; m < 4; ++m) {
        const int f0 = m * 16 + lrow * 4;
        #pragma unroll
        for (int n = 0; n < 4; ++n) {
            f32x4 v = acc[m][n];
            if (ACT == 1) {
                #pragma unroll
                for (int r = 0; r < 4; ++r) v[r] = gelu(v[r]);
            }
            uint2 pk;
            pk.x = pack2bf(v[0], v[1]);
            pk.y = pack2bf(v[2], v[3]);
            *(uint2*)&buf[(n * 16 + lcol) * SBW + f0] = pk;
        }
    }
}

template<int KT>
__device__ __forceinline__ void accInit(f32x4 (&acc)[4][4], const float* __restrict__ bias,
                                        int lrow) {
    #pragma unroll
    for (int m = 0; m < 4; ++m) {
        float4 bv = *(const float4*)(bias + m * 16 + lrow * 4);
        #pragma unroll
        for (int n = 0; n < 4; ++n) {
            acc[m][n][0] = bv.x; acc[m][n][1] = bv.y; acc[m][n][2] = bv.z; acc[m][n][3] = bv.w;
        }
    }
    (void)0;
}

template<int KT>
__device__ __forceinline__ void loadBB(bf16x8 (&bb)[4 * KT], const ushort_t* buf,
                                       int lrow, int lcol) {
    #pragma unroll
    for (int n = 0; n < 4; ++n)
        #pragma unroll
        for (int kt = 0; kt < KT; ++kt)
            bb[n * KT + kt] = *(const bf16x8*)&buf[(n * 16 + lcol) * SBW + kt * 32 + lrow * 8];
}

template<int KT>
__device__ __forceinline__ void mfmaHL(f32x4 (&acc)[4][4], const bf16x8 (&wh)[4 * KT],
                                       const bf16x8 (&wl)[4 * KT], const bf16x8 (&bb)[4 * KT]) {
    #pragma unroll
    for (int kt = 0; kt < KT; ++kt)
        #pragma unroll
        for (int m = 0; m < 4; ++m)
            #pragma unroll
            for (int n = 0; n < 4; ++n) {
                acc[m][n] = __builtin_amdgcn_mfma_f32_16x16x32_bf16(wh[m * KT + kt], bb[n * KT + kt], acc[m][n], 0, 0, 0);
                acc[m][n] = __builtin_amdgcn_mfma_f32_16x16x32_bf16(wl[m * KT + kt], bb[n * KT + kt], acc[m][n], 0, 0, 0);
            }
}

__global__ __launch_bounds__(64, 1)
void node_mfma_kernel(const float* __restrict__ pos, const int* __restrict__ z,
                      const ushort_t* __restrict__ wb,
                      const float* __restrict__ b_rbf0, const float* __restrict__ b_rbf1,
                      const float* __restrict__ b_m0, const float* __restrict__ b_m1,
                      const float* __restrict__ bc,
                      ushort_t* __restrict__ Tout, int N, int ntiles)
{
    __shared__ ushort_t buf[64 * SBW];   // 9216 B, private to this single wave
    const int lane = threadIdx.x;
    const int lrow = lane >> 4, lcol = lane & 15;
    const ushort_t* tab_bf = wb + 40960;

    // ---- persistent weight fragments: L2..L5 hi+lo (64 x bf16x8 = 256 VGPRs) ----
    bf16x8 w2h[8], w2l[8], w3h[8], w3l[8], w4h[8], w4l[8], w5h[8], w5l[8];
    #pragma unroll
    for (int m = 0; m < 4; ++m)
        #pragma unroll
        for (int kt = 0; kt < 2; ++kt) {
            const int i  = m * 2 + kt;
            const int o  = (m * 16 + lcol) * 64 + kt * 32 + lrow * 8;
            const int o3 = (m * 16 + lcol) * 96 + kt * 32 + lrow * 8;
            w2h[i] = *(const bf16x8*)(wb + 4096  + o);
            w2l[i] = *(const bf16x8*)(wb + 8192  + o);
            w3h[i] = *(const bf16x8*)(wb + 12288 + o3);
            w3l[i] = *(const bf16x8*)(wb + 18432 + o3);
            w4h[i] = *(const bf16x8*)(wb + 24576 + o);
            w4l[i] = *(const bf16x8*)(wb + 28672 + o);
            w5h[i] = *(const bf16x8*)(wb + 32768 + o);
            w5l[i] = *(const bf16x8*)(wb + 36864 + o);
        }

    for (int tile = blockIdx.x; tile < ntiles; tile += gridDim.x) {
        const int nodebase = tile * 64;
        int gn = nodebase + lane;
        if (gn > N - 1) gn = N - 1;

        // ---- stage rbf (32 cols) into own row ----
        {
            const float px = pos[3 * gn], py = pos[3 * gn + 1], pz = pos[3 * gn + 2];
            const float dist = sqrtf(px * px + py * py + pz * pz);
            unsigned rb[16];
            #pragma unroll
            for (int j = 0; j < 16; ++j) {
                float d0 = dist - (float)(2 * j)     * (1.0f / 31.0f);
                float d1 = dist - (float)(2 * j + 1) * (1.0f / 31.0f);
                rb[j] = pack2bf(__builtin_amdgcn_exp2f(-693.2149671554846f * d0 * d0),
                                __builtin_amdgcn_exp2f(-693.2149671554846f * d1 * d1));
            }
            uint4* dst = (uint4*)&buf[lane * SBW];
            dst[0] = make_uint4(rb[0], rb[1], rb[2], rb[3]);
            dst[1] = make_uint4(rb[4], rb[5], rb[6], rb[7]);
            dst[2] = make_uint4(rb[8], rb[9], rb[10], rb[11]);
            dst[3] = make_uint4(rb[12], rb[13], rb[14], rb[15]);
        }
        ds_order_fence();

        f32x4 acc[4][4];

        // ---- L1: gelu(rbf @ W_rbf0 + b), K=32, streamed weights ----
        {
            bf16x8 w1h[4], w1l[4], bb[4];
            #pragma unroll
            for (int m = 0; m < 4; ++m) {
                const int o = (m * 16 + lcol) * 32 + lrow * 8;
                w1h[m] = *(const bf16x8*)(wb + 0    + o);
                w1l[m] = *(const bf16x8*)(wb + 2048 + o);
            }
            accInit<1>(acc, b_rbf0, lrow);
            loadBB<1>(bb, buf, lrow, lcol);
            mfmaHL<1>(acc, w1h, w1l, bb);
            ds_order_fence();
            epilogueR<1>(acc, buf, lrow, lcol);
        }
        ds_order_fence();

        // ---- L2: r @ W_rbf1 + b (no act), K=64, persistent ----
        {
            bf16x8 bb[8];
            accInit<2>(acc, b_rbf1, lrow);
            loadBB<2>(bb, buf, lrow, lcol);
            mfmaHL<2>(acc, w2h, w2l, bb);
            ds_order_fence();
            epilogueR<0>(acc, buf, lrow, lcol);
        }
        ds_order_fence();

        // ---- L3: gelu([r|table] @ W_m0 + b), K=64 LDS + 32 table gather ----
        {
            bf16x8 bb[8], th[4], tl[4], tb[4];
            #pragma unroll
            for (int m = 0; m < 4; ++m) {
                const int o3 = (m * 16 + lcol) * 96 + 64 + lrow * 8;
                th[m] = *(const bf16x8*)(wb + 12288 + o3);
                tl[m] = *(const bf16x8*)(wb + 18432 + o3);
            }
            #pragma unroll
            for (int n = 0; n < 4; ++n) {
                int node = nodebase + n * 16 + lcol;
                if (node > N - 1) node = N - 1;
                tb[n] = *(const bf16x8*)(tab_bf + z[node] * 32 + lrow * 8);
            }
            accInit<2>(acc, b_m0, lrow);
            loadBB<2>(bb, buf, lrow, lcol);
            mfmaHL<2>(acc, w3h, w3l, bb);
            #pragma unroll
            for (int m = 0; m < 4; ++m)
                #pragma unroll
                for (int n = 0; n < 4; ++n) {
                    acc[m][n] = __builtin_amdgcn_mfma_f32_16x16x32_bf16(th[m], tb[n], acc[m][n], 0, 0, 0);
                    acc[m][n] = __builtin_amdgcn_mfma_f32_16x16x32_bf16(tl[m], tb[n], acc[m][n], 0, 0, 0);
                }
            ds_order_fence();
            epilogueR<1>(acc, buf, lrow, lcol);
        }
        ds_order_fence();

        // ---- L4: gelu(h @ W_m1 + b), K=64, persistent ----
        {
            bf16x8 bb[8];
            accInit<2>(acc, b_m1, lrow);
            loadBB<2>(bb, buf, lrow, lcol);
            mfmaHL<2>(acc, w4h, w4l, bb);
            ds_order_fence();
            epilogueR<1>(acc, buf, lrow, lcol);
        }
        ds_order_fence();

        // ---- L5: t = h @ Wc + bc, K=64, persistent ----
        {
            bf16x8 bb[8];
            accInit<2>(acc, bc, lrow);
            loadBB<2>(bb, buf, lrow, lcol);
            mfmaHL<2>(acc, w5h, w5l, bb);
            ds_order_fence();
            epilogueR<0>(acc, buf, lrow, lcol);
        }
        ds_order_fence();

        // ---- stream the 64x64 bf16 tile out fully coalesced (8 x 1KB stores) ----
        {
            ushort_t* tb2 = Tout + (size_t)nodebase * 64;
            #pragma unroll
            for (int i = 0; i < 8; ++i) {
                const int r = i * 8 + (lane >> 3);
                bf16x8 v = *(const bf16x8*)&buf[r * SBW + (lane & 7) * 8];
                if (nodebase + r < N)
                    *(bf16x8*)(tb2 + i * 512 + lane * 8) = v;
            }
        }
        ds_order_fence();
    }
}

// ---------------- per-graph reduction + Lcomb matmul ----------------
__global__ __launch_bounds__(256)
void graph_kernel(const ushort_t* __restrict__ Tin, const float* __restrict__ pos,
                  const int* __restrict__ seg, const float* __restrict__ Lcomb,
                  float* __restrict__ out, int G) {
    __shared__ float g1s[4][64][3];
    const int lane = threadIdx.x & 63;
    const int wid = threadIdx.x >> 6;
    const int g = blockIdx.x * 4 + wid;
    const bool active = g < G;

    if (active) {
        const int s = seg[g], e = seg[g + 1];
        float a0 = 0.f, a1 = 0.f, a2 = 0.f;
        for (int nn = s; nn < e; ++nn) {
            float t = bf2f(Tin[(size_t)nn * 64 + lane]);   // coalesced 128B/wave
            float qx = pos[3 * nn + 0], qy = pos[3 * nn + 1], qz = pos[3 * nn + 2];
            a0 = fmaf(t, qx, a0);
            a1 = fmaf(t, qy, a1);
            a2 = fmaf(t, qz, a2);
        }
        float cnt = (float)((e - s) > 0 ? (e - s) : 1);
        float sc = 1.7320508075688772f * 0.125f * (1.0f + 1.0f / cnt);
        g1s[wid][lane][0] = a0 * sc;
        g1s[wid][lane][1] = a1 * sc;
        g1s[wid][lane][2] = a2 * sc;
    }
    __syncthreads();
    if (!active) return;

    float o0 = 0.f, o1 = 0.f, o2 = 0.f, p0 = 0.f, p1 = 0.f, p2 = 0.f;
    const int v2 = 64 + lane;
    for (int u = 0; u < 64; ++u) {
        float b0 = g1s[wid][u][0], b1 = g1s[wid][u][1], b2 = g1s[wid][u][2];
        float l0 = Lcomb[u * 85 + lane];
        o0 = fmaf(b0, l0, o0); o1 = fmaf(b1, l0, o1); o2 = fmaf(b2, l0, o2);
        if (lane < 21) {
            float l1 = Lcomb[u * 85 + v2];
            p0 = fmaf(b0, l1, p0); p1 = fmaf(b1, l1, p1); p2 = fmaf(b2, l1, p2);
        }
    }
    float* og = out + (size_t)g * 255;
    og[3 * lane + 0] = o0; og[3 * lane + 1] = o1; og[3 * lane + 2] = o2;
    if (lane < 21) {
        og[3 * v2 + 0] = p0; og[3 * v2 + 1] = p1; og[3 * v2 + 2] = p2;
    }
}

extern "C" void kernel_launch(void* const* d_in, const int* in_sizes, int n_in,
                              void* d_out, int out_size, void* d_ws, size_t ws_size,
                              hipStream_t stream) {
    const float* pos        = (const float*)d_in[0];
    const int*   z          = (const int*)d_in[1];
    const int*   batch      = (const int*)d_in[2];
    const float* node_table = (const float*)d_in[3];
    const float* W_rbf0     = (const float*)d_in[4];
    const float* b_rbf0     = (const float*)d_in[5];
    const float* W_rbf1     = (const float*)d_in[6];
    const float* b_rbf1     = (const float*)d_in[7];
    const float* W_m0       = (const float*)d_in[8];
    const float* b_m0       = (const float*)d_in[9];
    const float* W_m1       = (const float*)d_in[10];
    const float* b_m1       = (const float*)d_in[11];
    const float* W_m2       = (const float*)d_in[12];
    const float* b_m2       = (const float*)d_in[13];
    const float* w_tp1      = (const float*)d_in[15];
    const float* L1o        = (const float*)d_in[18];
    const float* L_out      = (const float*)d_in[20];
    float* out = (float*)d_out;

    const int N = in_sizes[0] / 3;       // 200000
    const int G = out_size / 255;        // 8192
    const int ntiles = (N + 63) / 64;

    char* ws = (char*)d_ws;
    float*    bc    = (float*)(ws + 0);          // 256 B
    float*    Lcomb = (float*)(ws + 256);        // 21760 -> 22016, pad 22528
    int*      seg   = (int*)(ws + 22528);        // 32772 -> 55300, pad 55552
    ushort_t* wb    = (ushort_t*)(ws + 55552);   // 44160 ush = 88320 B -> 143872, pad 144128
    ushort_t* T     = (ushort_t*)(ws + 144128);  // ntiles*64*64*2 = 25.6 MB

    const int segBlocks = (N + 255) / 256;
    prep_kernel<<<115 + segBlocks, 256, 0, stream>>>(
        W_rbf0, W_rbf1, W_m0, W_m1, W_m2, b_m2, w_tp1, L1o, L_out,
        node_table, batch, wb, bc, Lcomb, seg, N, G);

    const int nodeBlocks = ntiles < 1024 ? ntiles : 1024;
    node_mfma_kernel<<<nodeBlocks, 64, 0, stream>>>(
        pos, z, wb, b_rbf0, b_rbf1, b_m0, b_m1, bc, T, N, ntiles);

    graph_kernel<<<(G + 3) / 4, 256, 0, stream>>>(T, pos, seg, Lcomb, out, G);
}

// Round 7
// 88.197 us; speedup vs baseline: 1.1241x; 1.1241x over previous
//
#include <hip/hip_runtime.h>

// Only the l=1 path reaches the output (g0/g2/c0/c2/w_tp0/w_tp2/L0/L2e are dead).
// t[i] = MLP(node i) @ (W_m2@w_tp1) + b_m2@w_tp1 ; enc = agg(segsum(t x sqrt3*pos)) @ (L1o@L_out)/64
// Node MLP on MFMA bf16, weights split hi+lo bf16 (error ~ f32). One wave = 64 nodes.
// KEY (r7): all 5 layers uniformized to K=64 and run in a NON-UNROLLED loop so the
// hot body (~3KB) is I$-resident — r4-r6 were instruction-fetch-bound (~30KB bodies).
//  - L1: W_rbf0 zero-padded to K=64 (rbf stage writes zero cols 32..63)
//  - L3: table contribution folded into acc-init via tblc[z][64] = b_m0 + table[z]@W_m0[64:96]

typedef __attribute__((ext_vector_type(8))) short bf16x8;
typedef __attribute__((ext_vector_type(4))) float f32x4;
typedef unsigned short ushort_t;

#define SBW 72   // LDS act-row stride in ushorts: 64 cols + 8 pad (144B rows, 16B-aligned)

__device__ __forceinline__ unsigned rnebits(float x) {   // RNE-rounded, bf16 in top 16 bits
    unsigned u = __float_as_uint(x);
    return u + 0x7fffu + ((u >> 16) & 1u);
}
__device__ __forceinline__ ushort_t f2bf(float x) { return (ushort_t)(rnebits(x) >> 16); }
__device__ __forceinline__ float bf2f(ushort_t h) { return __uint_as_float(((unsigned)h) << 16); }
__device__ __forceinline__ unsigned pack2bf(float lo, float hi) {   // lo -> low halfword
    return (rnebits(hi) & 0xffff0000u) | (rnebits(lo) >> 16);
}
__device__ __forceinline__ void ds_order_fence() {   // DS ops may not cross; VALU/MFMA/VMEM may
    __builtin_amdgcn_sched_barrier(0x7F);
}

// gelu(x) = x - x * rcp(exp2(x*(C + Ca*x^2)) + 1);  C = 2*0.79788456*log2(e)
__device__ __forceinline__ float gelu(float x) {
    float x2 = x * x;
    float y  = x * fmaf(0.10294324f, x2, 2.3022082f);
    float e  = __builtin_amdgcn_exp2f(y);
    float r  = __builtin_amdgcn_rcpf(e + 1.0f);
    return fmaf(-x, r, x);
}

// ---------------- prep ----------------
// wb ushort layout: layer L hi at L*8192, lo at L*8192+4096, all [64 feat][64 k] row-major.
//  L0=W_rbf0 zero-padded | L1=W_rbf1 | L2=W_m0[0:64] | L3=W_m1 | L4=Wc=W_m2@w_tp1
__global__ __launch_bounds__(256)
void prep_kernel(const float* __restrict__ W_rbf0, const float* __restrict__ W_rbf1,
                 const float* __restrict__ W_m0, const float* __restrict__ W_m1,
                 const float* __restrict__ W_m2, const float* __restrict__ b_m0,
                 const float* __restrict__ b_m2, const float* __restrict__ w_tp1,
                 const float* __restrict__ L1o, const float* __restrict__ L_out,
                 const float* __restrict__ node_table, const int* __restrict__ batch,
                 ushort_t* __restrict__ wb, float* __restrict__ tblc,
                 float* __restrict__ bc, float* __restrict__ Lcomb,
                 int* __restrict__ seg, int N, int G)
{
    if (blockIdx.x >= 127) {   // ---- seg part ----
        int i = (blockIdx.x - 127) * 256 + threadIdx.x;
        if (i >= N) return;
        int bi = batch[i];
        int bprev = (i == 0) ? -1 : batch[i - 1];
        for (int g = bprev + 1; g <= bi; ++g) seg[g] = i;
        if (i == N - 1) for (int g = bi + 1; g <= G; ++g) seg[g] = N;
        return;
    }
    int idx = blockIdx.x * 256 + threadIdx.x;   // fold part, 32384 items
    float w;
    ushort_t *dh, *dl;
    if (idx < 4096) {                    // L0: W_rbf0 zero-padded [f][64]
        int f = idx >> 6, k = idx & 63;
        w = (k < 32) ? W_rbf0[k * 64 + f] : 0.0f;
        dh = wb + idx; dl = wb + 4096 + idx;
    } else if (idx < 8192) {             // L1: W_rbf1 [f][64]
        int j = idx - 4096, f = j >> 6, k = j & 63;
        w = W_rbf1[k * 64 + f]; dh = wb + 8192 + j; dl = wb + 12288 + j;
    } else if (idx < 12288) {            // L2: W_m0 rows 0..63 [f][64]
        int j = idx - 8192, f = j >> 6, k = j & 63;
        w = W_m0[k * 64 + f]; dh = wb + 16384 + j; dl = wb + 20480 + j;
    } else if (idx < 16384) {            // L3: W_m1 [f][64]
        int j = idx - 12288, f = j >> 6, k = j & 63;
        w = W_m1[k * 64 + f]; dh = wb + 24576 + j; dl = wb + 28672 + j;
    } else if (idx < 20480) {            // L4: Wc[f][k] = sum_j W_m2[k][j]*w_tp1[j][f]
        int j = idx - 16384, f = j >> 6, k = j & 63;
        float s = 0.f;
        for (int jj = 0; jj < 64; ++jj) s = fmaf(W_m2[k * 64 + jj], w_tp1[jj * 64 + f], s);
        w = s; dh = wb + 32768 + j; dl = wb + 36864 + j;
    } else if (idx < 26880) {            // tblc[zz][f] = b_m0[f] + table[zz]@W_m0[64:96]  (f32)
        int j = idx - 20480, zz = j >> 6, f = j & 63;
        float s = b_m0[f];
        for (int k = 0; k < 32; ++k) s = fmaf(node_table[zz * 32 + k], W_m0[(64 + k) * 64 + f], s);
        tblc[j] = s;
        return;
    } else if (idx < 26944) {            // bc
        int b = idx - 26880;
        float s = 0.f;
        for (int k = 0; k < 64; ++k) s = fmaf(b_m2[k], w_tp1[k * 64 + b], s);
        bc[b] = s;
        return;
    } else if (idx < 32384) {            // Lcomb = (L1o@L_out)/64
        int j = idx - 26944, u = j / 85, v = j - 85 * u;
        float s = 0.f;
        for (int k = 0; k < 64; ++k) s = fmaf(L1o[u * 64 + k], L_out[k * 85 + v], s);
        Lcomb[j] = 0.015625f * s;
        return;
    } else return;
    ushort_t h = f2bf(w);
    *dh = h;
    *dl = f2bf(w - bf2f(h));
}

// ---------------- node MLP: one wave = 64 nodes, 5 uniform K=64 layers in a loop ----------------
__global__ __launch_bounds__(64, 4)
void node_mfma_kernel(const float* __restrict__ pos, const int* __restrict__ z,
                      const ushort_t* __restrict__ wb,
                      const float* __restrict__ tblc,
                      const float* __restrict__ b_rbf0, const float* __restrict__ b_rbf1,
                      const float* __restrict__ b_m1, const float* __restrict__ bc,
                      ushort_t* __restrict__ Tout, int N)
{
    __shared__ ushort_t buf[64 * SBW];   // 9216 B
    const int lane = threadIdx.x;
    const int lrow = lane >> 4, lcol = lane & 15;
    const int nodebase = blockIdx.x * 64;
    int gn = nodebase + lane;
    if (gn > N - 1) gn = N - 1;

    // ---- stage rbf (cols 0..31) + zeros (cols 32..63) into own row ----
    {
        const float px = pos[3 * gn], py = pos[3 * gn + 1], pz = pos[3 * gn + 2];
        const float dist = sqrtf(px * px + py * py + pz * pz);
        unsigned rb[16];
        #pragma unroll
        for (int j = 0; j < 16; ++j) {
            float d0 = dist - (float)(2 * j)     * (1.0f / 31.0f);
            float d1 = dist - (float)(2 * j + 1) * (1.0f / 31.0f);
            rb[j] = pack2bf(__builtin_amdgcn_exp2f(-693.2149671554846f * d0 * d0),
                            __builtin_amdgcn_exp2f(-693.2149671554846f * d1 * d1));
        }
        uint4* dst = (uint4*)&buf[lane * SBW];
        dst[0] = make_uint4(rb[0], rb[1], rb[2], rb[3]);
        dst[1] = make_uint4(rb[4], rb[5], rb[6], rb[7]);
        dst[2] = make_uint4(rb[8], rb[9], rb[10], rb[11]);
        dst[3] = make_uint4(rb[12], rb[13], rb[14], rb[15]);
        uint4 zz = make_uint4(0, 0, 0, 0);
        dst[4] = zz; dst[5] = zz; dst[6] = zz; dst[7] = zz;
    }
    // z gather for layer 2 acc-init (node = n*16+lcol per n)
    int zn0, zn1, zn2, zn3;
    {
        int n0 = nodebase + 0  + lcol; if (n0 > N - 1) n0 = N - 1;
        int n1 = nodebase + 16 + lcol; if (n1 > N - 1) n1 = N - 1;
        int n2 = nodebase + 32 + lcol; if (n2 > N - 1) n2 = N - 1;
        int n3 = nodebase + 48 + lcol; if (n3 > N - 1) n3 = N - 1;
        zn0 = z[n0]; zn1 = z[n1]; zn2 = z[n2]; zn3 = z[n3];
    }
    ds_order_fence();

    #pragma unroll 1
    for (int L = 0; L < 5; ++L) {
        const ushort_t* whb = wb + L * 8192;
        f32x4 acc[4][4];
        if (L == 2) {   // per-node acc-init from tblc (f32-exact table contribution)
            const int zn[4] = {zn0, zn1, zn2, zn3};
            #pragma unroll
            for (int n = 0; n < 4; ++n) {
                const float* tp = tblc + zn[n] * 64 + lrow * 4;
                #pragma unroll
                for (int m = 0; m < 4; ++m) {
                    float4 bv = *(const float4*)(tp + m * 16);
                    acc[m][n][0] = bv.x; acc[m][n][1] = bv.y;
                    acc[m][n][2] = bv.z; acc[m][n][3] = bv.w;
                }
            }
        } else {
            const float* bp = (L == 0) ? b_rbf0 : (L == 1) ? b_rbf1 : (L == 3) ? b_m1 : bc;
            #pragma unroll
            for (int m = 0; m < 4; ++m) {
                float4 bv = *(const float4*)(bp + m * 16 + lrow * 4);
                #pragma unroll
                for (int n = 0; n < 4; ++n) {
                    acc[m][n][0] = bv.x; acc[m][n][1] = bv.y;
                    acc[m][n][2] = bv.z; acc[m][n][3] = bv.w;
                }
            }
        }
        #pragma unroll
        for (int kt = 0; kt < 2; ++kt) {
            const int kof = kt * 32 + lrow * 8;
            bf16x8 bb[4];
            #pragma unroll
            for (int n = 0; n < 4; ++n)
                bb[n] = *(const bf16x8*)&buf[(n * 16 + lcol) * SBW + kof];
            #pragma unroll
            for (int m = 0; m < 4; ++m) {
                bf16x8 ah = *(const bf16x8*)(whb + (m * 16 + lcol) * 64 + kof);
                bf16x8 al = *(const bf16x8*)(whb + 4096 + (m * 16 + lcol) * 64 + kof);
                #pragma unroll
                for (int n = 0; n < 4; ++n) {
                    acc[m][n] = __builtin_amdgcn_mfma_f32_16x16x32_bf16(ah, bb[n], acc[m][n], 0, 0, 0);
                    acc[m][n] = __builtin_amdgcn_mfma_f32_16x16x32_bf16(al, bb[n], acc[m][n], 0, 0, 0);
                }
            }
        }
        ds_order_fence();   // all reads of buf done before in-place writes
        if ((L == 0) | (L == 2) | (L == 3)) {
            #pragma unroll
            for (int m = 0; m < 4; ++m) {
                const int f0 = m * 16 + lrow * 4;
                #pragma unroll
                for (int n = 0; n < 4; ++n) {
                    f32x4 v = acc[m][n];
                    uint2 pk;
                    pk.x = pack2bf(gelu(v[0]), gelu(v[1]));
                    pk.y = pack2bf(gelu(v[2]), gelu(v[3]));
                    *(uint2*)&buf[(n * 16 + lcol) * SBW + f0] = pk;
                }
            }
        } else {
            #pragma unroll
            for (int m = 0; m < 4; ++m) {
                const int f0 = m * 16 + lrow * 4;
                #pragma unroll
                for (int n = 0; n < 4; ++n) {
                    f32x4 v = acc[m][n];
                    uint2 pk;
                    pk.x = pack2bf(v[0], v[1]);
                    pk.y = pack2bf(v[2], v[3]);
                    *(uint2*)&buf[(n * 16 + lcol) * SBW + f0] = pk;
                }
            }
        }
        ds_order_fence();   // writes done before next layer's reads
    }

    // ---- stream the 64x64 bf16 tile out fully coalesced (8 x 1KB stores) ----
    {
        ushort_t* tb2 = Tout + (size_t)nodebase * 64;
        #pragma unroll
        for (int i = 0; i < 8; ++i) {
            const int r = i * 8 + (lane >> 3);
            bf16x8 v = *(const bf16x8*)&buf[r * SBW + (lane & 7) * 8];
            if (nodebase + r < N)
                *(bf16x8*)(tb2 + i * 512 + lane * 8) = v;
        }
    }
}

// ---------------- per-graph reduction + Lcomb matmul ----------------
__global__ __launch_bounds__(256)
void graph_kernel(const ushort_t* __restrict__ Tin, const float* __restrict__ pos,
                  const int* __restrict__ seg, const float* __restrict__ Lcomb,
                  float* __restrict__ out, int G) {
    __shared__ float g1s[4][64][3];
    const int lane = threadIdx.x & 63;
    const int wid = threadIdx.x >> 6;
    const int g = blockIdx.x * 4 + wid;
    const bool active = g < G;

    if (active) {
        const int s = seg[g], e = seg[g + 1];
        float a0 = 0.f, a1 = 0.f, a2 = 0.f;
        for (int nn = s; nn < e; ++nn) {
            float t = bf2f(Tin[(size_t)nn * 64 + lane]);   // coalesced 128B/wave
            float qx = pos[3 * nn + 0], qy = pos[3 * nn + 1], qz = pos[3 * nn + 2];
            a0 = fmaf(t, qx, a0);
            a1 = fmaf(t, qy, a1);
            a2 = fmaf(t, qz, a2);
        }
        float cnt = (float)((e - s) > 0 ? (e - s) : 1);
        float sc = 1.7320508075688772f * 0.125f * (1.0f + 1.0f / cnt);
        g1s[wid][lane][0] = a0 * sc;
        g1s[wid][lane][1] = a1 * sc;
        g1s[wid][lane][2] = a2 * sc;
    }
    __syncthreads();
    if (!active) return;

    float o0 = 0.f, o1 = 0.f, o2 = 0.f, p0 = 0.f, p1 = 0.f, p2 = 0.f;
    const int v2 = 64 + lane;
    for (int u = 0; u < 64; ++u) {
        float b0 = g1s[wid][u][0], b1 = g1s[wid][u][1], b2 = g1s[wid][u][2];
        float l0 = Lcomb[u * 85 + lane];
        o0 = fmaf(b0, l0, o0); o1 = fmaf(b1, l0, o1); o2 = fmaf(b2, l0, o2);
        if (lane < 21) {
            float l1 = Lcomb[u * 85 + v2];
            p0 = fmaf(b0, l1, p0); p1 = fmaf(b1, l1, p1); p2 = fmaf(b2, l1, p2);
        }
    }
    float* og = out + (size_t)g * 255;
    og[3 * lane + 0] = o0; og[3 * lane + 1] = o1; og[3 * lane + 2] = o2;
    if (lane < 21) {
        og[3 * v2 + 0] = p0; og[3 * v2 + 1] = p1; og[3 * v2 + 2] = p2;
    }
}

extern "C" void kernel_launch(void* const* d_in, const int* in_sizes, int n_in,
                              void* d_out, int out_size, void* d_ws, size_t ws_size,
                              hipStream_t stream) {
    const float* pos        = (const float*)d_in[0];
    const int*   z          = (const int*)d_in[1];
    const int*   batch      = (const int*)d_in[2];
    const float* node_table = (const float*)d_in[3];
    const float* W_rbf0     = (const float*)d_in[4];
    const float* b_rbf0     = (const float*)d_in[5];
    const float* W_rbf1     = (const float*)d_in[6];
    const float* b_rbf1     = (const float*)d_in[7];
    const float* W_m0       = (const float*)d_in[8];
    const float* b_m0       = (const float*)d_in[9];
    const float* W_m1       = (const float*)d_in[10];
    const float* b_m1       = (const float*)d_in[11];
    const float* W_m2       = (const float*)d_in[12];
    const float* b_m2       = (const float*)d_in[13];
    const float* w_tp1      = (const float*)d_in[15];
    const float* L1o        = (const float*)d_in[18];
    const float* L_out      = (const float*)d_in[20];
    float* out = (float*)d_out;

    const int N = in_sizes[0] / 3;       // 200000
    const int G = out_size / 255;        // 8192
    const int ntiles = (N + 63) / 64;

    char* ws = (char*)d_ws;
    float*    bc    = (float*)(ws + 0);           // 256 B
    float*    Lcomb = (float*)(ws + 256);         // 21760 -> 22016, pad 22528
    int*      seg   = (int*)(ws + 22528);         // 32772 -> 55300, pad 55552
    ushort_t* wb    = (ushort_t*)(ws + 55552);    // 40960 ush = 81920 B -> 137472
    float*    tblc  = (float*)(ws + 137472);      // 100*64*4 = 25600 -> 163072
    ushort_t* T     = (ushort_t*)(ws + 163072);   // ntiles*64*64*2 = 25.6 MB

    const int segBlocks = (N + 255) / 256;
    prep_kernel<<<127 + segBlocks, 256, 0, stream>>>(
        W_rbf0, W_rbf1, W_m0, W_m1, W_m2, b_m0, b_m2, w_tp1, L1o, L_out,
        node_table, batch, wb, tblc, bc, Lcomb, seg, N, G);

    node_mfma_kernel<<<ntiles, 64, 0, stream>>>(
        pos, z, wb, tblc, b_rbf0, b_rbf1, b_m1, bc, T, N);

    graph_kernel<<<(G + 3) / 4, 256, 0, stream>>>(T, pos, seg, Lcomb, out, G);
}